// Round 1
// baseline (1364.658 us; speedup 1.0000x reference)
//
#include <hip/hip_runtime.h>
#include <hip/hip_bf16.h>

#define N_NODES 100000
#define N_EDGES 600000
#define CH 128
#define N_GRAPHS 100
#define BN_EPS 1e-5f

// ---------------------------------------------------------------------------
// K1: agg[dst[e]] += h[src[e]] * norm[src[e]]   (76.8M f32 atomics, 4 ch/thread)
// ---------------------------------------------------------------------------
__global__ __launch_bounds__(256) void scatter_kernel(
    const float* __restrict__ h, const float* __restrict__ norm,
    const int* __restrict__ src, const int* __restrict__ dst,
    float* __restrict__ agg)
{
    int t = blockIdx.x * 256 + threadIdx.x;   // [0, N_EDGES*32)
    int e  = t >> 5;
    int c  = (t & 31) << 2;                    // channel base, 4 floats
    if (e >= N_EDGES) return;
    int s = src[e], d = dst[e];
    float nm = norm[s];
    const float4 v = *(const float4*)(h + (size_t)s * CH + c);
    float* base = agg + (size_t)d * CH + c;
    atomicAdd(base + 0, v.x * nm);
    atomicAdd(base + 1, v.y * nm);
    atomicAdd(base + 2, v.z * nm);
    atomicAdd(base + 3, v.w * nm);
}

// ---------------------------------------------------------------------------
// K2: y = relu((agg * norm) @ W + b), written straight into d_out's x region.
// Block: 256 threads, 64-node M-tile, per-thread 8 nodes x 4 channels.
// ---------------------------------------------------------------------------
#define MT 64
__global__ __launch_bounds__(256) void gemm_relu_kernel(
    const float* __restrict__ agg, const float* __restrict__ norm,
    const float* __restrict__ W, const float* __restrict__ b,
    float* __restrict__ y)
{
    __shared__ float Ws[CH * CH];        // [k][o], 64 KB
    __shared__ float xs[MT][CH + 4];     // [m][k], stride 132 (16B-aligned rows)

    int tid = threadIdx.x;
    int n0  = blockIdx.x * MT;

    // Stage W (16384 floats = 4096 float4)
    const float4* W4 = (const float4*)W;
    float4* Ws4 = (float4*)Ws;
    #pragma unroll
    for (int i = 0; i < 16; i++) Ws4[tid + i * 256] = W4[tid + i * 256];

    // Stage x-tile: xs[m][k] = agg[n][k] * norm[n]
    #pragma unroll
    for (int i = tid; i < MT * 32; i += 256) {
        int r = i >> 5, c = (i & 31) << 2;
        int n = n0 + r;
        float4 v = make_float4(0.f, 0.f, 0.f, 0.f);
        float nm = 0.f;
        if (n < N_NODES) {
            v = *(const float4*)(agg + (size_t)n * CH + c);
            nm = norm[n];
        }
        xs[r][c + 0] = v.x * nm;
        xs[r][c + 1] = v.y * nm;
        xs[r][c + 2] = v.z * nm;
        xs[r][c + 3] = v.w * nm;
    }
    __syncthreads();

    int oi = tid & 31, mi = tid >> 5;
    int o = oi * 4, m0 = mi * 8;
    float acc[8][4] = {};

    for (int k = 0; k < CH; k += 4) {
        float4 w0 = *(float4*)&Ws[(k + 0) * CH + o];
        float4 w1 = *(float4*)&Ws[(k + 1) * CH + o];
        float4 w2 = *(float4*)&Ws[(k + 2) * CH + o];
        float4 w3 = *(float4*)&Ws[(k + 3) * CH + o];
        #pragma unroll
        for (int j = 0; j < 8; j++) {
            float4 xv = *(float4*)&xs[m0 + j][k];
            acc[j][0] += xv.x * w0.x + xv.y * w1.x + xv.z * w2.x + xv.w * w3.x;
            acc[j][1] += xv.x * w0.y + xv.y * w1.y + xv.z * w2.y + xv.w * w3.y;
            acc[j][2] += xv.x * w0.z + xv.y * w1.z + xv.z * w2.z + xv.w * w3.z;
            acc[j][3] += xv.x * w0.w + xv.y * w1.w + xv.z * w2.w + xv.w * w3.w;
        }
    }

    float4 bv = *(const float4*)(b + o);
    #pragma unroll
    for (int j = 0; j < 8; j++) {
        int n = n0 + m0 + j;
        if (n < N_NODES) {
            float4 r;
            r.x = fmaxf(acc[j][0] + bv.x, 0.f);
            r.y = fmaxf(acc[j][1] + bv.y, 0.f);
            r.z = fmaxf(acc[j][2] + bv.z, 0.f);
            r.w = fmaxf(acc[j][3] + bv.w, 0.f);
            *(float4*)(y + (size_t)n * CH + o) = r;
        }
    }
}

// ---------------------------------------------------------------------------
// K3: per-channel sum & sumsq (block-partial + one atomic per block per ch)
// ---------------------------------------------------------------------------
#define STAT_ROWS 256
__global__ __launch_bounds__(128) void bn_stats_kernel(
    const float* __restrict__ y, float* __restrict__ sums, float* __restrict__ sumsq)
{
    int t = threadIdx.x;
    int r0 = blockIdx.x * STAT_ROWS;
    if (r0 >= N_NODES) return;
    int rend = min(r0 + STAT_ROWS, N_NODES);
    float s = 0.f, q = 0.f;
    for (int r = r0; r < rend; r++) {
        float v = y[(size_t)r * CH + t];
        s += v;
        q += v * v;
    }
    atomicAdd(&sums[t], s);
    atomicAdd(&sumsq[t], q);
}

// ---------------------------------------------------------------------------
// K4: scale = gamma * rsqrt(var + eps);  shift = beta - mean * scale
// ---------------------------------------------------------------------------
__global__ void bn_finalize_kernel(
    const float* __restrict__ sums, const float* __restrict__ sumsq,
    const float* __restrict__ gamma, const float* __restrict__ beta,
    float* __restrict__ scale, float* __restrict__ shift)
{
    int t = threadIdx.x;
    const float invN = 1.f / (float)N_NODES;
    float mean = sums[t] * invN;
    float var  = sumsq[t] * invN - mean * mean;
    float sc   = gamma[t] * rsqrtf(var + BN_EPS);
    scale[t] = sc;
    shift[t] = beta[t] - mean * sc;
}

// ---------------------------------------------------------------------------
// K5: x = y*scale+shift (in-place in d_out) + per-graph pooled sum.
// graph_ids is sorted -> per-block running segment sum, ~1 atomic per
// (block, graph-boundary) per channel instead of one per node.
// ---------------------------------------------------------------------------
#define POOL_ROWS 256
__global__ __launch_bounds__(128) void bn_pool_kernel(
    float* __restrict__ y, const int* __restrict__ gids,
    const float* __restrict__ scale, const float* __restrict__ shift,
    float* __restrict__ phis)
{
    int t = threadIdx.x;
    int r0 = blockIdx.x * POOL_ROWS;
    if (r0 >= N_NODES) return;
    int rend = min(r0 + POOL_ROWS, N_NODES);
    float sc = scale[t], sh = shift[t];
    float local = 0.f;
    int cur = gids[r0];
    for (int r = r0; r < rend; r++) {
        int g = gids[r];                       // uniform across block
        if (g != cur) {
            atomicAdd(&phis[(size_t)cur * CH + t], local);
            local = 0.f;
            cur = g;
        }
        float v = fmaf(y[(size_t)r * CH + t], sc, sh);
        y[(size_t)r * CH + t] = v;             // in-place: read-once write-once
        local += v;
    }
    atomicAdd(&phis[(size_t)cur * CH + t], local);
}

// ---------------------------------------------------------------------------
extern "C" void kernel_launch(void* const* d_in, const int* in_sizes, int n_in,
                              void* d_out, int out_size, void* d_ws, size_t ws_size,
                              hipStream_t stream)
{
    const float* h     = (const float*)d_in[0];   // [N,128]
    const float* norm  = (const float*)d_in[1];   // [N,1]
    const float* W     = (const float*)d_in[2];   // [128,128]
    const float* b     = (const float*)d_in[3];   // [128]
    const float* gamma = (const float*)d_in[4];   // [128]
    const float* beta  = (const float*)d_in[5];   // [128]
    const int*   src   = (const int*)d_in[6];     // [E]
    const int*   dst   = (const int*)d_in[7];     // [E]
    const int*   gids  = (const int*)d_in[8];     // [N], sorted

    float* x_out = (float*)d_out;                       // [N,128]
    float* phis  = x_out + (size_t)N_NODES * CH;        // [100,128]

    float* agg   = (float*)d_ws;                        // [N,128]
    float* sums  = agg + (size_t)N_NODES * CH;          // [128]
    float* sumsq = sums + CH;                           // [128]
    float* scale = sumsq + CH;                          // [128]
    float* shift = scale + CH;                          // [128]

    hipMemsetAsync(agg, 0, (size_t)N_NODES * CH * sizeof(float), stream);
    hipMemsetAsync(sums, 0, 2 * CH * sizeof(float), stream);
    hipMemsetAsync(phis, 0, (size_t)N_GRAPHS * CH * sizeof(float), stream);

    scatter_kernel<<<(N_EDGES * 32) / 256, 256, 0, stream>>>(h, norm, src, dst, agg);
    gemm_relu_kernel<<<(N_NODES + MT - 1) / MT, 256, 0, stream>>>(agg, norm, W, b, x_out);
    bn_stats_kernel<<<(N_NODES + STAT_ROWS - 1) / STAT_ROWS, 128, 0, stream>>>(x_out, sums, sumsq);
    bn_finalize_kernel<<<1, 128, 0, stream>>>(sums, sumsq, gamma, beta, scale, shift);
    bn_pool_kernel<<<(N_NODES + POOL_ROWS - 1) / POOL_ROWS, 128, 0, stream>>>(x_out, gids, scale, shift, phis);
}

// Round 2
// 486.993 us; speedup vs baseline: 2.8022x; 2.8022x over previous
//
#include <hip/hip_runtime.h>
#include <hip/hip_bf16.h>

#define N_NODES 100000
#define N_EDGES 600000
#define CH 128
#define N_GRAPHS 100
#define BN_EPS 1e-5f
#define NCHUNK 391          // ceil(N_NODES/256)

// ---------------------------------------------------------------------------
// CSR build: histogram of dst -> exclusive scan -> bucket fill (src values)
// ---------------------------------------------------------------------------
__global__ __launch_bounds__(256) void k_hist(const int* __restrict__ dst, int* __restrict__ cnt) {
    int e = blockIdx.x * 256 + threadIdx.x;
    if (e < N_EDGES) atomicAdd(&cnt[dst[e]], 1);
}

__global__ __launch_bounds__(64) void k_chunksum(const int* __restrict__ cnt, int* __restrict__ partials) {
    int base = blockIdx.x * 256 + threadIdx.x * 4;
    int s = 0;
    #pragma unroll
    for (int i = 0; i < 4; i++) { int idx = base + i; if (idx < N_NODES) s += cnt[idx]; }
    #pragma unroll
    for (int off = 32; off; off >>= 1) s += __shfl_down(s, off);
    if (threadIdx.x == 0) partials[blockIdx.x] = s;
}

__global__ __launch_bounds__(512) void k_scanpartials(int* __restrict__ partials) {
    __shared__ int sm[512];
    int t = threadIdx.x;
    int v = (t < NCHUNK) ? partials[t] : 0;
    sm[t] = v; __syncthreads();
    for (int off = 1; off < 512; off <<= 1) {
        int add = (t >= off) ? sm[t - off] : 0;
        __syncthreads();
        sm[t] += add;
        __syncthreads();
    }
    if (t < NCHUNK) partials[t] = sm[t] - v;   // exclusive
}

__global__ __launch_bounds__(256) void k_scatteroffs(const int* __restrict__ cnt,
        const int* __restrict__ partials, int* __restrict__ offs, int* __restrict__ cursor) {
    __shared__ int sm[256];
    int t = threadIdx.x;
    int i = blockIdx.x * 256 + t;
    int v = (i < N_NODES) ? cnt[i] : 0;
    sm[t] = v; __syncthreads();
    for (int off = 1; off < 256; off <<= 1) {
        int add = (t >= off) ? sm[t - off] : 0;
        __syncthreads();
        sm[t] += add;
        __syncthreads();
    }
    int excl = sm[t] - v + partials[blockIdx.x];
    if (i < N_NODES) { offs[i] = excl; cursor[i] = excl; }
    if (i == 0) offs[N_NODES] = N_EDGES;
}

__global__ __launch_bounds__(256) void k_fill(const int* __restrict__ src, const int* __restrict__ dst,
        int* __restrict__ cursor, int* __restrict__ esrc) {
    int e = blockIdx.x * 256 + threadIdx.x;
    if (e < N_EDGES) {
        int p = atomicAdd(&cursor[dst[e]], 1);
        esrc[p] = src[e];
    }
}

// ---------------------------------------------------------------------------
// Gather: x2[n] = norm[n] * sum_{edges into n} h[s]*norm[s]   (no atomics)
// 32 threads per node, float4 per thread.
// ---------------------------------------------------------------------------
__global__ __launch_bounds__(256) void k_gather(const float* __restrict__ h,
        const float* __restrict__ norm, const int* __restrict__ offs,
        const int* __restrict__ esrc, float* __restrict__ x2) {
    int t = blockIdx.x * 256 + threadIdx.x;
    int n = t >> 5;
    int c = (t & 31) << 2;
    if (n >= N_NODES) return;
    int j0 = offs[n], j1 = offs[n + 1];
    float4 acc = make_float4(0.f, 0.f, 0.f, 0.f);
    for (int j = j0; j < j1; j++) {
        int s = esrc[j];                              // broadcast within 32 lanes
        float nm = norm[s];
        float4 v = *(const float4*)(h + (size_t)s * CH + c);
        acc.x += v.x * nm; acc.y += v.y * nm; acc.z += v.z * nm; acc.w += v.w * nm;
    }
    float nn = norm[n];
    acc.x *= nn; acc.y *= nn; acc.z *= nn; acc.w *= nn;
    *(float4*)(x2 + (size_t)n * CH + c) = acc;
}

// ---------------------------------------------------------------------------
// GEMM + ReLU + fused BN stats. Block 256, 64-node tile, 8x4 per thread.
// W read from global (L1/L2 broadcast). LDS = x-tile only -> 4 blocks/CU.
// ---------------------------------------------------------------------------
#define MT 64
__global__ __launch_bounds__(256) void k_gemm(const float* __restrict__ x2,
        const float* __restrict__ W, const float* __restrict__ b,
        float* __restrict__ y, float* __restrict__ sums, float* __restrict__ sumsq) {
    __shared__ float xs[MT][CH + 4];   // 33.8 KB

    int tid = threadIdx.x;
    int n0 = blockIdx.x * MT;

    #pragma unroll
    for (int i = tid; i < MT * 32; i += 256) {
        int r = i >> 5, c = (i & 31) << 2;
        int n = n0 + r;
        float4 v = make_float4(0.f, 0.f, 0.f, 0.f);
        if (n < N_NODES) v = *(const float4*)(x2 + (size_t)n * CH + c);
        *(float4*)&xs[r][c] = v;
    }
    __syncthreads();

    int oi = tid & 31, mi = tid >> 5;
    int o = oi * 4, m0 = mi * 8;
    float acc[8][4] = {};

    #pragma unroll 4
    for (int k = 0; k < CH; k += 4) {
        float4 w0 = *(const float4*)(W + (size_t)(k + 0) * CH + o);
        float4 w1 = *(const float4*)(W + (size_t)(k + 1) * CH + o);
        float4 w2 = *(const float4*)(W + (size_t)(k + 2) * CH + o);
        float4 w3 = *(const float4*)(W + (size_t)(k + 3) * CH + o);
        #pragma unroll
        for (int j = 0; j < 8; j++) {
            float4 xv = *(float4*)&xs[m0 + j][k];
            acc[j][0] += xv.x * w0.x + xv.y * w1.x + xv.z * w2.x + xv.w * w3.x;
            acc[j][1] += xv.x * w0.y + xv.y * w1.y + xv.z * w2.y + xv.w * w3.y;
            acc[j][2] += xv.x * w0.z + xv.y * w1.z + xv.z * w2.z + xv.w * w3.z;
            acc[j][3] += xv.x * w0.w + xv.y * w1.w + xv.z * w2.w + xv.w * w3.w;
        }
    }

    float4 bv = *(const float4*)(b + o);
    float4 s4 = make_float4(0.f, 0.f, 0.f, 0.f);
    float4 q4 = make_float4(0.f, 0.f, 0.f, 0.f);
    #pragma unroll
    for (int j = 0; j < 8; j++) {
        int n = n0 + m0 + j;
        if (n < N_NODES) {
            float4 r;
            r.x = fmaxf(acc[j][0] + bv.x, 0.f);
            r.y = fmaxf(acc[j][1] + bv.y, 0.f);
            r.z = fmaxf(acc[j][2] + bv.z, 0.f);
            r.w = fmaxf(acc[j][3] + bv.w, 0.f);
            *(float4*)(y + (size_t)n * CH + o) = r;
            s4.x += r.x; s4.y += r.y; s4.z += r.z; s4.w += r.w;
            q4.x += r.x * r.x; q4.y += r.y * r.y; q4.z += r.z * r.z; q4.w += r.w * r.w;
        }
    }

    // cross-thread reduce over the 8 mi-groups (reuse xs LDS)
    __syncthreads();
    float* red = &xs[0][0];                  // need 256*8 = 2048 floats, have 8448
    *(float4*)&red[tid * 8 + 0] = s4;
    *(float4*)&red[tid * 8 + 4] = q4;
    __syncthreads();
    if (mi == 0) {
        float4 S = make_float4(0.f, 0.f, 0.f, 0.f);
        float4 Q = make_float4(0.f, 0.f, 0.f, 0.f);
        #pragma unroll
        for (int g = 0; g < 8; g++) {
            float4 a = *(float4*)&red[(g * 32 + oi) * 8 + 0];
            float4 q = *(float4*)&red[(g * 32 + oi) * 8 + 4];
            S.x += a.x; S.y += a.y; S.z += a.z; S.w += a.w;
            Q.x += q.x; Q.y += q.y; Q.z += q.z; Q.w += q.w;
        }
        atomicAdd(&sums[o + 0], S.x); atomicAdd(&sums[o + 1], S.y);
        atomicAdd(&sums[o + 2], S.z); atomicAdd(&sums[o + 3], S.w);
        atomicAdd(&sumsq[o + 0], Q.x); atomicAdd(&sumsq[o + 1], Q.y);
        atomicAdd(&sumsq[o + 2], Q.z); atomicAdd(&sumsq[o + 3], Q.w);
    }
}

// ---------------------------------------------------------------------------
__global__ void k_finalize(const float* __restrict__ sums, const float* __restrict__ sumsq,
        const float* __restrict__ gamma, const float* __restrict__ beta,
        float* __restrict__ scale, float* __restrict__ shift) {
    int t = threadIdx.x;
    const float invN = 1.f / (float)N_NODES;
    float mean = sums[t] * invN;
    float var  = sumsq[t] * invN - mean * mean;
    float sc   = gamma[t] * rsqrtf(var + BN_EPS);
    scale[t] = sc;
    shift[t] = beta[t] - mean * sc;
}

// ---------------------------------------------------------------------------
// BN apply (in-place) + per-graph pooling. Block 256 = 32 ch-lanes x 8 row-lanes,
// 64 rows per block. Run-length segment accumulation -> few atomics.
// ---------------------------------------------------------------------------
#define PR 64
__global__ __launch_bounds__(256) void k_pool(float* __restrict__ y, const int* __restrict__ gids,
        const float* __restrict__ scale, const float* __restrict__ shift, float* __restrict__ phis) {
    int tid = threadIdx.x;
    int cl = tid & 31, rl = tid >> 5;
    int c = cl * 4;
    int r0 = blockIdx.x * PR;
    float4 sc = *(const float4*)(scale + c);
    float4 sh = *(const float4*)(shift + c);
    float4 local = make_float4(0.f, 0.f, 0.f, 0.f);
    int cur = -1;
    #pragma unroll
    for (int j = 0; j < 8; j++) {
        int r = r0 + j * 8 + rl;
        if (r >= N_NODES) break;
        int g = gids[r];
        if (g != cur) {
            if (cur >= 0) {
                atomicAdd(&phis[(size_t)cur * CH + c + 0], local.x);
                atomicAdd(&phis[(size_t)cur * CH + c + 1], local.y);
                atomicAdd(&phis[(size_t)cur * CH + c + 2], local.z);
                atomicAdd(&phis[(size_t)cur * CH + c + 3], local.w);
            }
            local = make_float4(0.f, 0.f, 0.f, 0.f);
            cur = g;
        }
        float4 v = *(float4*)(y + (size_t)r * CH + c);
        v.x = fmaf(v.x, sc.x, sh.x);
        v.y = fmaf(v.y, sc.y, sh.y);
        v.z = fmaf(v.z, sc.z, sh.z);
        v.w = fmaf(v.w, sc.w, sh.w);
        *(float4*)(y + (size_t)r * CH + c) = v;
        local.x += v.x; local.y += v.y; local.z += v.z; local.w += v.w;
    }
    if (cur >= 0) {
        atomicAdd(&phis[(size_t)cur * CH + c + 0], local.x);
        atomicAdd(&phis[(size_t)cur * CH + c + 1], local.y);
        atomicAdd(&phis[(size_t)cur * CH + c + 2], local.z);
        atomicAdd(&phis[(size_t)cur * CH + c + 3], local.w);
    }
}

// ---------------------------------------------------------------------------
extern "C" void kernel_launch(void* const* d_in, const int* in_sizes, int n_in,
                              void* d_out, int out_size, void* d_ws, size_t ws_size,
                              hipStream_t stream)
{
    const float* h     = (const float*)d_in[0];
    const float* norm  = (const float*)d_in[1];
    const float* W     = (const float*)d_in[2];
    const float* b     = (const float*)d_in[3];
    const float* gamma = (const float*)d_in[4];
    const float* beta  = (const float*)d_in[5];
    const int*   src   = (const int*)d_in[6];
    const int*   dst   = (const int*)d_in[7];
    const int*   gids  = (const int*)d_in[8];

    float* x_out = (float*)d_out;                       // [N,128]
    float* phis  = x_out + (size_t)N_NODES * CH;        // [100,128]

    float* x2      = (float*)d_ws;                      // [N,128] normalized agg
    int*   cnt     = (int*)(x2 + (size_t)N_NODES * CH); // [N]
    int*   offs    = cnt + N_NODES;                     // [N+1]
    int*   cursor  = offs + N_NODES + 1;                // [N]
    int*   esrc    = cursor + N_NODES;                  // [E]
    int*   partials= esrc + N_EDGES;                    // [512]
    float* sums    = (float*)(partials + 512);          // [128]
    float* sumsq   = sums + CH;
    float* scale   = sumsq + CH;
    float* shift   = scale + CH;

    hipMemsetAsync(cnt, 0, (size_t)N_NODES * sizeof(int), stream);
    hipMemsetAsync(sums, 0, 2 * CH * sizeof(float), stream);
    hipMemsetAsync(phis, 0, (size_t)N_GRAPHS * CH * sizeof(float), stream);

    k_hist<<<(N_EDGES + 255) / 256, 256, 0, stream>>>(dst, cnt);
    k_chunksum<<<NCHUNK, 64, 0, stream>>>(cnt, partials);
    k_scanpartials<<<1, 512, 0, stream>>>(partials);
    k_scatteroffs<<<NCHUNK, 256, 0, stream>>>(cnt, partials, offs, cursor);
    k_fill<<<(N_EDGES + 255) / 256, 256, 0, stream>>>(src, dst, cursor, esrc);
    k_gather<<<(N_NODES * 32) / 256, 256, 0, stream>>>(h, norm, offs, esrc, x2);
    k_gemm<<<(N_NODES + MT - 1) / MT, 256, 0, stream>>>(x2, W, b, x_out, sums, sumsq);
    k_finalize<<<1, 128, 0, stream>>>(sums, sumsq, gamma, beta, scale, shift);
    k_pool<<<(N_NODES + PR - 1) / PR, 256, 0, stream>>>(x_out, gids, scale, shift, phis);
}

// Round 3
// 323.279 us; speedup vs baseline: 4.2213x; 1.5064x over previous
//
#include <hip/hip_runtime.h>
#include <hip/hip_bf16.h>

#define N_NODES 100000
#define N_PAD 100032         // 1563 blocks * 64 rows
#define N_EDGES 600000
#define CH 128
#define N_GRAPHS 100
#define BN_EPS 1e-5f
#define NCHUNK 391           // ceil(N_NODES/256)
#define NBUCKET 64

typedef __bf16 bf16x8 __attribute__((ext_vector_type(8)));
typedef float f32x4 __attribute__((ext_vector_type(4)));

__device__ __forceinline__ ushort f2bf(float f) {
    union { float f; unsigned u; } x; x.f = f;
    unsigned u = x.u;
    unsigned r = (u + 0x7fffu + ((u >> 16) & 1u)) >> 16;
    return (ushort)r;
}

// ---------------------------------------------------------------------------
// CSR build: histogram of dst -> exclusive scan -> bucket fill (src values)
// ---------------------------------------------------------------------------
__global__ __launch_bounds__(256) void k_hist(const int* __restrict__ dst, int* __restrict__ cnt) {
    int e = blockIdx.x * 256 + threadIdx.x;
    if (e < N_EDGES) atomicAdd(&cnt[dst[e]], 1);
}

__global__ __launch_bounds__(64) void k_chunksum(const int* __restrict__ cnt, int* __restrict__ partials) {
    int base = blockIdx.x * 256 + threadIdx.x * 4;
    int s = 0;
    #pragma unroll
    for (int i = 0; i < 4; i++) { int idx = base + i; if (idx < N_NODES) s += cnt[idx]; }
    #pragma unroll
    for (int off = 32; off; off >>= 1) s += __shfl_down(s, off);
    if (threadIdx.x == 0) partials[blockIdx.x] = s;
}

__global__ __launch_bounds__(512) void k_scanpartials(int* __restrict__ partials) {
    __shared__ int sm[512];
    int t = threadIdx.x;
    int v = (t < NCHUNK) ? partials[t] : 0;
    sm[t] = v; __syncthreads();
    for (int off = 1; off < 512; off <<= 1) {
        int add = (t >= off) ? sm[t - off] : 0;
        __syncthreads();
        sm[t] += add;
        __syncthreads();
    }
    if (t < NCHUNK) partials[t] = sm[t] - v;   // exclusive
}

__global__ __launch_bounds__(256) void k_scatteroffs(const int* __restrict__ cnt,
        const int* __restrict__ partials, int* __restrict__ offs, int* __restrict__ cursor) {
    __shared__ int sm[256];
    int t = threadIdx.x;
    int i = blockIdx.x * 256 + t;
    int v = (i < N_NODES) ? cnt[i] : 0;
    sm[t] = v; __syncthreads();
    for (int off = 1; off < 256; off <<= 1) {
        int add = (t >= off) ? sm[t - off] : 0;
        __syncthreads();
        sm[t] += add;
        __syncthreads();
    }
    int excl = sm[t] - v + partials[blockIdx.x];
    if (i < N_NODES) { offs[i] = excl; cursor[i] = excl; }
    if (i == 0) offs[N_NODES] = N_EDGES;
}

__global__ __launch_bounds__(256) void k_fill(const int* __restrict__ src, const int* __restrict__ dst,
        int* __restrict__ cursor, int* __restrict__ esrc) {
    int e = blockIdx.x * 256 + threadIdx.x;
    if (e < N_EDGES) {
        int p = atomicAdd(&cursor[dst[e]], 1);
        esrc[p] = src[e];
    }
}

// ---------------------------------------------------------------------------
// W [k][o] f32 -> Wt [o][k] bf16
// ---------------------------------------------------------------------------
__global__ __launch_bounds__(256) void k_convW(const float* __restrict__ W, ushort* __restrict__ Wt) {
    int t = blockIdx.x * 256 + threadIdx.x;       // 16384
    int k = t >> 7, o = t & 127;
    Wt[o * CH + k] = f2bf(W[t]);
}

// ---------------------------------------------------------------------------
// Gather: x2[n] = bf16( norm[n] * sum_in h[s]*norm[s] )  (f32 accumulate)
// 32 threads per node, 4 channels each.
// ---------------------------------------------------------------------------
__global__ __launch_bounds__(256) void k_gather(const float* __restrict__ h,
        const float* __restrict__ norm, const int* __restrict__ offs,
        const int* __restrict__ esrc, ushort* __restrict__ x2) {
    int t = blockIdx.x * 256 + threadIdx.x;
    int n = t >> 5;
    int c = (t & 31) << 2;
    if (n >= N_NODES) return;
    int j0 = offs[n], j1 = offs[n + 1];
    float4 acc = make_float4(0.f, 0.f, 0.f, 0.f);
    for (int j = j0; j < j1; j++) {
        int s = esrc[j];                              // broadcast within 32 lanes
        float nm = norm[s];
        float4 v = *(const float4*)(h + (size_t)s * CH + c);
        acc.x += v.x * nm; acc.y += v.y * nm; acc.z += v.z * nm; acc.w += v.w * nm;
    }
    float nn = norm[n];
    ushort4 o4;
    o4.x = f2bf(acc.x * nn); o4.y = f2bf(acc.y * nn);
    o4.z = f2bf(acc.z * nn); o4.w = f2bf(acc.w * nn);
    *(ushort4*)(x2 + (size_t)n * CH + c) = o4;
}

// ---------------------------------------------------------------------------
// MFMA GEMM: y = relu(x2 @ W + b), fused BN partial stats.
// Block 256 = 4 waves; wave w -> rows blk*64 + w*16, all 128 cols.
// A frag: x2 row segment (16B). B frag: Wt row segment (16B). No frag LDS.
// ---------------------------------------------------------------------------
__global__ __launch_bounds__(256) void k_gemm(const ushort* __restrict__ x2,
        const ushort* __restrict__ Wt, const float* __restrict__ bias,
        float* __restrict__ y, float* __restrict__ psum, float* __restrict__ psq) {
    __shared__ float smS[8 * 256];
    __shared__ float smQ[8 * 256];

    int tid = threadIdx.x;
    int w = tid >> 6, L = tid & 63;
    int c15 = L & 15, quad = L >> 4;
    size_t n0 = (size_t)blockIdx.x * 64 + w * 16;

    const bf16x8* Arow = (const bf16x8*)(x2 + (n0 + c15) * CH);

    f32x4 acc[8] = {};
    #pragma unroll
    for (int kt = 0; kt < 4; kt++) {
        bf16x8 a = Arow[kt * 4 + quad];
        #pragma unroll
        for (int ot = 0; ot < 8; ot++) {
            const bf16x8* Brow = (const bf16x8*)(Wt + (size_t)(ot * 16 + c15) * CH);
            bf16x8 b = Brow[kt * 4 + quad];
            acc[ot] = __builtin_amdgcn_mfma_f32_16x16x32_bf16(a, b, acc[ot], 0, 0, 0);
        }
    }

    // epilogue: bias + relu + store + per-lane stats
    #pragma unroll
    for (int ot = 0; ot < 8; ot++) {
        int col = ot * 16 + c15;
        float bv = bias[col];
        float s_ = 0.f, q_ = 0.f;
        #pragma unroll
        for (int r = 0; r < 4; r++) {
            size_t n = n0 + quad * 4 + r;
            float v = fmaxf(acc[ot][r] + bv, 0.f);
            if (n < N_NODES) {
                y[n * CH + col] = v;
                s_ += v; q_ += v * v;
            }
        }
        smS[ot * 256 + tid] = s_;
        smQ[ot * 256 + tid] = q_;
    }
    __syncthreads();

    if (tid < 128) {
        int ot = tid >> 4, cc = tid & 15;
        int col = ot * 16 + cc;
        float S = 0.f, Q = 0.f;
        #pragma unroll
        for (int g = 0; g < 16; g++) {
            int sl = (g >> 2) * 64 + (g & 3) * 16 + cc;
            S += smS[ot * 256 + sl];
            Q += smQ[ot * 256 + sl];
        }
        int bucket = blockIdx.x & (NBUCKET - 1);
        atomicAdd(&psum[bucket * CH + col], S);
        atomicAdd(&psq[bucket * CH + col], Q);
    }
}

// ---------------------------------------------------------------------------
__global__ void k_finalize(const float* __restrict__ psum, const float* __restrict__ psq,
        const float* __restrict__ gamma, const float* __restrict__ beta,
        float* __restrict__ scale, float* __restrict__ shift) {
    int t = threadIdx.x;   // 128
    float S = 0.f, Q = 0.f;
    for (int g = 0; g < NBUCKET; g++) { S += psum[g * CH + t]; Q += psq[g * CH + t]; }
    const float invN = 1.f / (float)N_NODES;
    float mean = S * invN;
    float var  = Q * invN - mean * mean;
    float sc   = gamma[t] * rsqrtf(var + BN_EPS);
    scale[t] = sc;
    shift[t] = beta[t] - mean * sc;
}

// ---------------------------------------------------------------------------
// BN apply (in-place) + per-graph pooling (sorted gids -> run-length atomics)
// ---------------------------------------------------------------------------
#define PR 64
__global__ __launch_bounds__(256) void k_pool(float* __restrict__ y, const int* __restrict__ gids,
        const float* __restrict__ scale, const float* __restrict__ shift, float* __restrict__ phis) {
    int tid = threadIdx.x;
    int cl = tid & 31, rl = tid >> 5;
    int c = cl * 4;
    int r0 = blockIdx.x * PR;
    float4 sc = *(const float4*)(scale + c);
    float4 sh = *(const float4*)(shift + c);
    float4 local = make_float4(0.f, 0.f, 0.f, 0.f);
    int cur = -1;
    #pragma unroll
    for (int j = 0; j < 8; j++) {
        int r = r0 + j * 8 + rl;
        if (r >= N_NODES) break;
        int g = gids[r];
        if (g != cur) {
            if (cur >= 0) {
                atomicAdd(&phis[(size_t)cur * CH + c + 0], local.x);
                atomicAdd(&phis[(size_t)cur * CH + c + 1], local.y);
                atomicAdd(&phis[(size_t)cur * CH + c + 2], local.z);
                atomicAdd(&phis[(size_t)cur * CH + c + 3], local.w);
            }
            local = make_float4(0.f, 0.f, 0.f, 0.f);
            cur = g;
        }
        float4 v = *(float4*)(y + (size_t)r * CH + c);
        v.x = fmaf(v.x, sc.x, sh.x);
        v.y = fmaf(v.y, sc.y, sh.y);
        v.z = fmaf(v.z, sc.z, sh.z);
        v.w = fmaf(v.w, sc.w, sh.w);
        *(float4*)(y + (size_t)r * CH + c) = v;
        local.x += v.x; local.y += v.y; local.z += v.z; local.w += v.w;
    }
    if (cur >= 0) {
        atomicAdd(&phis[(size_t)cur * CH + c + 0], local.x);
        atomicAdd(&phis[(size_t)cur * CH + c + 1], local.y);
        atomicAdd(&phis[(size_t)cur * CH + c + 2], local.z);
        atomicAdd(&phis[(size_t)cur * CH + c + 3], local.w);
    }
}

// ---------------------------------------------------------------------------
extern "C" void kernel_launch(void* const* d_in, const int* in_sizes, int n_in,
                              void* d_out, int out_size, void* d_ws, size_t ws_size,
                              hipStream_t stream)
{
    const float* h     = (const float*)d_in[0];
    const float* norm  = (const float*)d_in[1];
    const float* W     = (const float*)d_in[2];
    const float* b     = (const float*)d_in[3];
    const float* gamma = (const float*)d_in[4];
    const float* beta  = (const float*)d_in[5];
    const int*   src   = (const int*)d_in[6];
    const int*   dst   = (const int*)d_in[7];
    const int*   gids  = (const int*)d_in[8];

    float* x_out = (float*)d_out;                       // [N,128]
    float* phis  = x_out + (size_t)N_NODES * CH;        // [100,128]

    ushort* x2     = (ushort*)d_ws;                     // [N_PAD,128] bf16
    ushort* Wt     = x2 + (size_t)N_PAD * CH;           // [128,128] bf16 transposed
    int*   cnt     = (int*)(Wt + CH * CH);              // [N]
    int*   offs    = cnt + N_NODES;                     // [N+1]
    int*   cursor  = offs + N_NODES + 1;                // [N]
    int*   esrc    = cursor + N_NODES;                  // [E]
    int*   partials= esrc + N_EDGES;                    // [512]
    float* psum    = (float*)(partials + 512);          // [64,128]
    float* psq     = psum + NBUCKET * CH;               // [64,128]
    float* scale   = psq + NBUCKET * CH;                // [128]
    float* shift   = scale + CH;                        // [128]

    hipMemsetAsync(cnt, 0, (size_t)N_NODES * sizeof(int), stream);
    hipMemsetAsync(psum, 0, 2 * NBUCKET * CH * sizeof(float), stream);
    hipMemsetAsync(phis, 0, (size_t)N_GRAPHS * CH * sizeof(float), stream);

    k_hist<<<(N_EDGES + 255) / 256, 256, 0, stream>>>(dst, cnt);
    k_chunksum<<<NCHUNK, 64, 0, stream>>>(cnt, partials);
    k_scanpartials<<<1, 512, 0, stream>>>(partials);
    k_scatteroffs<<<NCHUNK, 256, 0, stream>>>(cnt, partials, offs, cursor);
    k_fill<<<(N_EDGES + 255) / 256, 256, 0, stream>>>(src, dst, cursor, esrc);
    k_convW<<<64, 256, 0, stream>>>(W, Wt);
    k_gather<<<(N_NODES * 32 + 255) / 256, 256, 0, stream>>>(h, norm, offs, esrc, x2);
    k_gemm<<<N_PAD / 64, 256, 0, stream>>>(x2, Wt, b, x_out, psum, psq);
    k_finalize<<<1, 128, 0, stream>>>(psum, psq, gamma, beta, scale, shift);
    k_pool<<<(N_NODES + PR - 1) / PR, 256, 0, stream>>>(x_out, gids, scale, shift, phis);
}